// Round 1
// baseline (1466.241 us; speedup 1.0000x reference)
//
#include <hip/hip_runtime.h>
#include <hip/hip_bf16.h>

// GCN layer: out = A_coo @ (X @ W^T + b)
// Plan: (1) GEMM -> xb (bf16, [N][128]) ; (2) histogram rows ; (3) prefix scan ;
// (4) scatter edges into row-sorted (col,val) pairs ; (5) per-row gather-reduce.

// ---- GEMM: xb[n][o] = bf16( sum_i in[n][i]*W[o][i] + b[o] ) ----
__global__ __launch_bounds__(256) void gemm_kernel(
    const float* __restrict__ in, const float* __restrict__ W,
    const float* __restrict__ bias, __hip_bfloat16* __restrict__ xb, int N) {
  __shared__ __hip_bfloat16 Ws[128 * 128];  // Ws[i*128+o] = W[o][i] (transposed), 32 KB
  __shared__ float rowbuf[4][128];
  const int tid = threadIdx.x;
  for (int idx = tid; idx < 128 * 128; idx += 256) {
    int o = idx >> 7, i = idx & 127;
    Ws[i * 128 + o] = __float2bfloat16(W[idx]);  // coalesced read of W
  }
  __syncthreads();
  const int lane = tid & 63;
  const int w = tid >> 6;
  const int gw = blockIdx.x * 4 + w;
  const int nw = gridDim.x * 4;
  const float2 bb = *reinterpret_cast<const float2*>(bias + 2 * lane);
  for (int n = gw; n < N; n += nw) {
    float2 rv = *reinterpret_cast<const float2*>(in + (size_t)n * 128 + 2 * lane);
    rowbuf[w][2 * lane] = rv.x;
    rowbuf[w][2 * lane + 1] = rv.y;
    float a0 = 0.f, a1 = 0.f;
#pragma unroll 8
    for (int i = 0; i < 128; ++i) {
      float xi = rowbuf[w][i];  // LDS broadcast
      unsigned wp = *reinterpret_cast<const unsigned*>(&Ws[i * 128 + 2 * lane]);
      a0 += xi * __uint_as_float(wp << 16);
      a1 += xi * __uint_as_float(wp & 0xffff0000u);
    }
    __hip_bfloat162 h;
    h.x = __float2bfloat16(a0 + bb.x);
    h.y = __float2bfloat16(a1 + bb.y);
    *reinterpret_cast<__hip_bfloat162*>(xb + (size_t)n * 128 + 2 * lane) = h;
  }
}

// ---- histogram of destination rows ----
__global__ void hist_kernel(const int* __restrict__ rows, int* __restrict__ counts, int E) {
  int i = blockIdx.x * blockDim.x + threadIdx.x;
  int stride = gridDim.x * blockDim.x;
  for (; i < E; i += stride) atomicAdd(&counts[rows[i]], 1);
}

// ---- single-block exclusive prefix scan over counts[N] -> offsets, cursor ----
__global__ __launch_bounds__(1024) void scan_kernel(const int* __restrict__ counts,
    int* __restrict__ offsets, int* __restrict__ cursor, int N) {
  __shared__ int lds[1024];
  const int t = threadIdx.x;
  const int seg = (N + 1023) >> 10;
  const int base = t * seg;
  int s = 0;
  for (int k = 0; k < seg; ++k) {
    int i = base + k;
    if (i < N) s += counts[i];
  }
  lds[t] = s;
  __syncthreads();
  for (int off = 1; off < 1024; off <<= 1) {
    int v = (t >= off) ? lds[t - off] : 0;
    __syncthreads();
    lds[t] += v;
    __syncthreads();
  }
  int run = (t == 0) ? 0 : lds[t - 1];
  if (t == 0) offsets[N] = lds[1023];
  for (int k = 0; k < seg; ++k) {
    int i = base + k;
    if (i < N) {
      offsets[i] = run;
      cursor[i] = run;
      run += counts[i];
    }
  }
}

// ---- scatter edges into row-sorted order (packed col+val, one 8B write) ----
__global__ void scatter_kernel(const int* __restrict__ rows, const int* __restrict__ cols,
    const float* __restrict__ vals, int* __restrict__ cursor, int2* __restrict__ epack, int E) {
  int i = blockIdx.x * blockDim.x + threadIdx.x;
  int stride = gridDim.x * blockDim.x;
  for (; i < E; i += stride) {
    int r = rows[i];
    int p = atomicAdd(&cursor[r], 1);
    epack[p] = make_int2(cols[i], __float_as_int(vals[i]));
  }
}

// ---- per-row gather-reduce: one wave per row, 2 features per lane ----
__global__ __launch_bounds__(256) void reduce_kernel(const int* __restrict__ offsets,
    const int2* __restrict__ epack, const __hip_bfloat16* __restrict__ xb,
    float* __restrict__ out, int N) {
  const int lane = threadIdx.x & 63;
  const int w = threadIdx.x >> 6;
  const int r = blockIdx.x * 4 + w;
  if (r >= N) return;
  const int start = offsets[r];
  const int end = offsets[r + 1];
  float a0 = 0.f, a1 = 0.f;
  const unsigned* xbu = reinterpret_cast<const unsigned*>(xb);
  for (int k = start; k < end; k += 64) {
    int nb = end - k;
    if (nb > 64) nb = 64;
    int c = 0;
    float v = 0.f;
    if (lane < nb) {
      int2 ep = epack[k + lane];
      c = ep.x;
      v = __int_as_float(ep.y);
    }
#pragma unroll 4
    for (int j = 0; j < nb; ++j) {
      int cj = __shfl(c, j);
      float vj = __shfl(v, j);
      unsigned pv = xbu[cj * 64 + lane];  // wave reads 256B contiguous row of xb
      a0 += vj * __uint_as_float(pv << 16);
      a1 += vj * __uint_as_float(pv & 0xffff0000u);
    }
  }
  *reinterpret_cast<float2*>(out + (size_t)r * 128 + 2 * lane) = make_float2(a0, a1);
}

extern "C" void kernel_launch(void* const* d_in, const int* in_sizes, int n_in,
                              void* d_out, int out_size, void* d_ws, size_t ws_size,
                              hipStream_t stream) {
  const float* layer_input = (const float*)d_in[0];
  const int* adj_rows = (const int*)d_in[1];
  const int* adj_cols = (const int*)d_in[2];
  const float* adj_vals = (const float*)d_in[3];
  const float* W = (const float*)d_in[4];
  const float* bias = (const float*)d_in[5];
  float* out = (float*)d_out;
  const int N = in_sizes[0] / 128;
  const int E = in_sizes[1];

  char* ws = (char*)d_ws;
  size_t off = 0;
  __hip_bfloat16* xb = (__hip_bfloat16*)(ws + off); off += (size_t)N * 128 * 2;
  int* counts = (int*)(ws + off);  off += ((size_t)N * 4 + 15) & ~15ull;
  int* offsets = (int*)(ws + off); off += ((size_t)(N + 1) * 4 + 15) & ~15ull;
  int* cursor = (int*)(ws + off);  off += ((size_t)N * 4 + 15) & ~15ull;
  int2* epack = (int2*)(ws + off); off += (size_t)E * 8;
  // total ~78 MB of d_ws

  hipMemsetAsync(counts, 0, (size_t)N * 4, stream);
  gemm_kernel<<<1024, 256, 0, stream>>>(layer_input, W, bias, xb, N);
  hist_kernel<<<2048, 256, 0, stream>>>(adj_rows, counts, E);
  scan_kernel<<<1, 1024, 0, stream>>>(counts, offsets, cursor, N);
  scatter_kernel<<<2048, 256, 0, stream>>>(adj_rows, adj_cols, adj_vals, cursor, epack, E);
  reduce_kernel<<<(N + 3) / 4, 256, 0, stream>>>(offsets, epack, xb, out, N);
}